// Round 12
// baseline (314.782 us; speedup 1.0000x reference)
//
#include <hip/hip_runtime.h>
#include <math.h>

// ---- problem constants ----
#define N_NODES 33
#define SEQ 24
#define BATCH 64
#define G_GRAPHS (BATCH * SEQ)          // 1536
#define EPG 64
#define E_EDGES (G_GRAPHS * EPG)        // 98304
#define N_TOTAL (G_GRAPHS * N_NODES)    // 50688
#define HID 64
#define HEADS 8
#define HC (HID * HEADS)                // 512
#define LSTM1_H 128
#define LSTM2_H 64
#define N_CLASSES 4
#define NEG_SLOPE 0.2f
// conv fused into gat1 chunk 0: 128 transpose tiles + 264 W1f blocks
#define CONV_BLOCKS (128 + 264)

// ---- fast transcendentals (round-25, verified: gat1 74.7 -> <64us,
// absmax unchanged): v_exp_f32-based, ~2-3 insts vs ~15-20 libm.
__device__ __forceinline__ float sigmoidf_(float x) { return 1.f / (1.f + __expf(-x)); }
__device__ __forceinline__ float eluf_(float x) { return x > 0.f ? x : __expf(x) - 1.f; }
__device__ __forceinline__ float lreluf_(float x) { return x > 0.f ? x : NEG_SLOPE * x; }
__device__ __forceinline__ float tanhf_(float x) {
  float t = __expf(-2.f * fabsf(x));       // t in (0,1], no inf/NaN
  float r = (1.f - t) / (1.f + t);
  return x >= 0.f ? r : -r;
}

typedef __attribute__((ext_vector_type(4))) float f32x4;
typedef _Float16 half_t;
typedef __attribute__((ext_vector_type(8))) _Float16 halfx8;
typedef __attribute__((ext_vector_type(2))) _Float16 half2_t;

__device__ __forceinline__ void gl2lds16(const void* g, void* l) {
  __builtin_amdgcn_global_load_lds(
      (__attribute__((address_space(1))) const unsigned int*)g,
      (__attribute__((address_space(3))) unsigned int*)l, 16, 0, 0);
}

// ============================================================
// GAT layer 1, 512 threads (8 waves). Blocks >= gat_blocks do the one-time
// fp16 weight conversion: 128 LDS-transpose tiles + 264 elementwise W1f blocks.
// ============================================================
__global__ __launch_bounds__(512) void gat1_kernel(
    const float* __restrict__ x, const int* __restrict__ src, const int* __restrict__ dst,
    const float* __restrict__ ea, const float* __restrict__ Wl, const float* __restrict__ Wr,
    const float* __restrict__ We, const float* __restrict__ att, const float* __restrict__ bias,
    half_t* __restrict__ h1, int g0, int gat_blocks,
    const float* __restrict__ g2Wl, const float* __restrict__ g2Wr,
    half_t* __restrict__ B2, const float* __restrict__ W1, half_t* __restrict__ W1f) {
  const int tid = threadIdx.x;

  __shared__ alignas(16) float Wl_s[2 * 512];
  __shared__ alignas(16) float Wr_s[2 * 512];
  __shared__ alignas(16) float We_s[3 * 512];
  __shared__ alignas(16) float att_s[512];
  __shared__ float xs0_s[N_NODES + 1], xs1_s[N_NODES + 1];
  __shared__ float easX[EPG], easY[EPG], easZ[EPG];
  __shared__ float logit_s[HEADS * 65];
  __shared__ int sloc[EPG], dloc[EPG], deg[N_NODES], start[N_NODES], fill[N_NODES], elist[EPG];
  __shared__ float tr[64 * 65];          // transpose tile (conv path)

  if ((int)blockIdx.x >= gat_blocks) {
    int cb = blockIdx.x - gat_blocks;
    if (cb < 128) {
      // transpose B2[n][k] = [Wl|Wr][k][n], 64x64 tile, coalesced both ways
      int kt = cb & 7, nt = cb >> 3;
      int k0 = kt * 64, n0 = nt * 64;
      int r = tid >> 6, c = tid & 63;
      #pragma unroll
      for (int rr = 0; rr < 8; ++rr) {
        int kl = rr * 8 + r;
        int n = n0 + c;
        float v = (n < 512) ? g2Wl[(size_t)(k0 + kl) * 512 + n]
                            : g2Wr[(size_t)(k0 + kl) * 512 + n - 512];
        tr[kl * 65 + c] = v;
      }
      __syncthreads();
      #pragma unroll
      for (int rr = 0; rr < 8; ++rr) {
        int nl = rr * 8 + r;
        B2[(size_t)(n0 + nl) * 512 + k0 + c] = (half_t)tr[c * 65 + nl];
      }
    } else {
      int base = (cb - 128) * 4096 + tid;
      #pragma unroll
      for (int i = 0; i < 8; ++i) {
        int idx = base + i * 512;
        if (idx < 512 * 2112) W1f[idx] = (half_t)W1[idx];
      }
    }
    return;
  }

  const int g = g0 + blockIdx.x;
  const int nb = g * N_NODES, eb = g * EPG;
  const int lb = blockIdx.x * N_NODES;

  for (int i = tid; i < 1024; i += 512) { Wl_s[i] = Wl[i]; Wr_s[i] = Wr[i]; }
  for (int i = tid; i < 1536; i += 512) We_s[i] = We[i];
  if (tid < 512) att_s[tid] = att[tid];
  if (tid < 2 * N_NODES) {
    float v = x[nb * 2 + tid];
    if (tid & 1) xs1_s[tid >> 1] = v; else xs0_s[tid >> 1] = v;
  }
  if (tid < EPG) {
    easX[tid] = ea[(eb + tid) * 3 + 0];
    easY[tid] = ea[(eb + tid) * 3 + 1];
    easZ[tid] = ea[(eb + tid) * 3 + 2];
    sloc[tid] = src[eb + tid] - nb;
    dloc[tid] = dst[eb + tid] - nb;
  }
  if (tid < N_NODES) { deg[tid] = 0; fill[tid] = 0; }
  __syncthreads();
  if (tid < EPG) atomicAdd(&deg[dloc[tid]], 1);
  __syncthreads();
  if (tid == 0) { int a = 0; for (int n = 0; n < N_NODES; ++n) { start[n] = a; a += deg[n]; } }
  __syncthreads();
  if (tid < EPG) { int d = dloc[tid]; int p = atomicAdd(&fill[d], 1); elist[start[d] + p] = tid; }

  // logits: one pass, h = tid>>6 (wave-uniform), e = lane
  {
    int h = tid >> 6, e = tid & 63;
    int s = sloc[e], d = dloc[e];
    float xs0 = xs0_s[s], xs1 = xs1_s[s], xd0 = xs0_s[d], xd1 = xs1_s[d];
    float e0 = easX[e], e1 = easY[e], e2 = easZ[e];
    float acc = 0.f;
    int base = h * 64;
    #pragma unroll
    for (int c4 = 0; c4 < 16; ++c4) {
      int j = base + c4 * 4;
      f32x4 wl0 = *(const f32x4*)(Wl_s + j);
      f32x4 wl1 = *(const f32x4*)(Wl_s + 512 + j);
      f32x4 wr0 = *(const f32x4*)(Wr_s + j);
      f32x4 wr1 = *(const f32x4*)(Wr_s + 512 + j);
      f32x4 we0 = *(const f32x4*)(We_s + j);
      f32x4 we1 = *(const f32x4*)(We_s + 512 + j);
      f32x4 we2 = *(const f32x4*)(We_s + 1024 + j);
      f32x4 at  = *(const f32x4*)(att_s + j);
      #pragma unroll
      for (int q = 0; q < 4; ++q) {
        float v = xs0 * wl0[q] + xs1 * wl1[q]
                + xd0 * wr0[q] + xd1 * wr1[q]
                + e0 * we0[q] + e1 * we1[q] + e2 * we2[q];
        acc += lreluf_(v) * at[q];
      }
    }
    logit_s[h * 65 + e] = acc;
  }
  __syncthreads();

  // segment softmax: one pass, h = tid>>6, n = lane (skip n>=33); exp deduped
  {
    int h = tid >> 6, n = tid & 63;
    if (n < N_NODES) {
      int s0 = start[n], dn = deg[n];
      float mx = -1e30f;
      for (int i = 0; i < dn; ++i) mx = fmaxf(mx, logit_s[h * 65 + elist[s0 + i]]);
      float den = 0.f;
      for (int i = 0; i < dn; ++i) {
        int e = elist[s0 + i];
        float ex = __expf(logit_s[h * 65 + e] - mx);
        logit_s[h * 65 + e] = ex;
        den += ex;
      }
      float inv = 1.f / (den + 1e-16f);
      for (int i = 0; i < dn; ++i) logit_s[h * 65 + elist[s0 + i]] *= inv;
    }
  }
  __syncthreads();

  // aggregation: task = (n, 8-channel block); n = t>>6 wave-uniform, jb = lane
  for (int t = tid; t < N_NODES * 64; t += 512) {
    int n = t >> 6, jb = t & 63;
    int j0 = jb * 8, h = jb >> 3;
    f32x4 wa0 = *(const f32x4*)(Wl_s + j0);
    f32x4 wa1 = *(const f32x4*)(Wl_s + j0 + 4);
    f32x4 wb0 = *(const f32x4*)(Wl_s + 512 + j0);
    f32x4 wb1 = *(const f32x4*)(Wl_s + 512 + j0 + 4);
    float acc[8] = {};
    int s0 = start[n], dn = deg[n];
    for (int i = 0; i < dn; ++i) {
      int e = elist[s0 + i]; int s = sloc[e];
      float a = logit_s[h * 65 + e];
      float ax0 = a * xs0_s[s], ax1 = a * xs1_s[s];
      #pragma unroll
      for (int q = 0; q < 4; ++q) {
        acc[q]     += ax0 * wa0[q] + ax1 * wb0[q];
        acc[4 + q] += ax0 * wa1[q] + ax1 * wb1[q];
      }
    }
    f32x4 b0 = *(const f32x4*)(bias + j0);
    f32x4 b1 = *(const f32x4*)(bias + j0 + 4);
    halfx8 vh;
    #pragma unroll
    for (int cc = 0; cc < 8; ++cc) {
      float bb = (cc < 4) ? b0[cc] : b1[cc - 4];
      vh[cc] = (half_t)eluf_(acc[cc] + bb);
    }
    *(halfx8*)(h1 + (size_t)(lb + n) * HC + j0) = vh;
  }
}

// ============================================================
// Main GEMM (round-19/round-8 verified: ~64us, 832 TF = 95% of the m97
// structure ceiling, FETCH 31.4MB, 0 bank conflicts). ROUND-9 LESSON:
// static XCD-affine grid beats work-stealing here (stealing: FETCH
// 31->158 MB). Rounds 1/2: deep pipelines at this K=512 shape are worse.
// This kernel is DONE.
// ============================================================
#define LDA8(S, rr, c) \
  (*(const halfx8*)((S) + (rr) * 64 + ((((c) ^ ((rr) & 7))) << 3)))

__global__ __launch_bounds__(256, 4) void gemm_m97(
    const half_t* __restrict__ A, const half_t* __restrict__ B,
    half_t* __restrict__ C, int M) {
  // staging: A 128x64 + B 128x64 halfs = 32 KB; C-bounce 128x132 = 33 KB
  __shared__ alignas(16) half_t lds[128 * 132];

  half_t* const As = lds;                // 8192 halfs
  half_t* const Bs = lds + 8192;         // 8192 halfs

  const int R = M >> 7;                  // row tiles
  const int nwg = R * 8;                 // 8 col tiles; nwg % 8 == 0
  const int cpx = nwg >> 3;
  const int bid = blockIdx.x;
  const int swz = (bid & 7) * cpx + (bid >> 3);  // bijective XCD swizzle
  const int ct = swz & 7, r = swz >> 3;          // ct fast: A-panel L2 reuse

  const int tid = threadIdx.x;
  const int wave = tid >> 6, lane = tid & 63;
  const int wm = wave >> 1, wn = wave & 1;       // 2x2 waves, 64x64 each
  const int bm = r << 7, bn = ct << 7;

  // staging: lane -> row rl of 8-row group, pre-swizzled global chunk
  const int rl = lane >> 3;
  const int gc = ((lane & 7) ^ rl) << 3;
  // fragment read: row fr in 16-row tile, k-quarter kq
  const int fr = lane & 15;
  const int kq = lane >> 4;

  f32x4 acc[4][4];
  #pragma unroll
  for (int tm = 0; tm < 4; ++tm)
    #pragma unroll
    for (int tn = 0; tn < 4; ++tn) acc[tm][tn] = {0.f, 0.f, 0.f, 0.f};

  for (int t = 0; t < 8; ++t) {
    // stage K-tile t: A 128x64 + B 128x64, 8 gl2lds16 per wave
    #pragma unroll
    for (int i = 0; i < 4; ++i) {
      int r0 = i * 32 + wave * 8;
      gl2lds16(A + (size_t)(bm + r0 + rl) * 512 + t * 64 + gc, As + r0 * 64);
    }
    #pragma unroll
    for (int i = 0; i < 4; ++i) {
      int r0 = i * 32 + wave * 8;
      gl2lds16(B + (size_t)(bn + r0 + rl) * 512 + t * 64 + gc, Bs + r0 * 64);
    }
    __syncthreads();   // compiler drains vmcnt before barrier

    #pragma unroll
    for (int ks = 0; ks < 2; ++ks) {
      halfx8 af[4], bf[4];
      #pragma unroll
      for (int tm = 0; tm < 4; ++tm)
        af[tm] = LDA8(As, wm * 64 + tm * 16 + fr, ks * 4 + kq);
      #pragma unroll
      for (int tn = 0; tn < 4; ++tn)
        bf[tn] = LDA8(Bs, wn * 64 + tn * 16 + fr, ks * 4 + kq);
      #pragma unroll
      for (int tm = 0; tm < 4; ++tm)
        #pragma unroll
        for (int tn = 0; tn < 4; ++tn)
          acc[tm][tn] = __builtin_amdgcn_mfma_f32_16x16x32_f16(
              af[tm], bf[tn], acc[tm][tn], 0, 0, 0);
    }
    __syncthreads();   // protect LDS overwrite next K-step
  }

  // epilogue: fp16 bounce through LDS (stride 132), coalesced halfx8 stores
  half_t* Cs = lds;
  const int rq4 = (lane >> 4) * 4;
  const int cl0 = lane & 15;
  #pragma unroll
  for (int tm = 0; tm < 4; ++tm)
    #pragma unroll
    for (int tn = 0; tn < 4; ++tn) {
      int cl = wn * 64 + tn * 16 + cl0;
      #pragma unroll
      for (int rr = 0; rr < 4; ++rr)
        Cs[(wm * 64 + tm * 16 + rq4 + rr) * 132 + cl] = (half_t)acc[tm][tn][rr];
    }
  __syncthreads();
  #pragma unroll
  for (int pass = 0; pass < 8; ++pass) {
    int row = pass * 16 + (tid >> 4);
    int col = (tid & 15) * 8;
    halfx8 v = *(const halfx8*)(Cs + row * 132 + col);
    *(halfx8*)(C + (size_t)(bm + row) * 1024 + bn + col) = v;
  }
}

// ============================================================
// final GEMM, split-K=4 in one dispatch (round-14 verified)
// ============================================================
__global__ __launch_bounds__(256) void gemm_f16_splitk(
    const half_t* __restrict__ A, const half_t* __restrict__ B,
    float* __restrict__ Cp, const float* __restrict__ bias1, const float* __restrict__ bias2,
    int M, int N) {
  constexpr int SA = 2112;
  __shared__ half_t lds[(64 + 64) * 64];
  half_t* A_s = lds;
  half_t* B_s = A_s + 2 * 64 * 32;

  const int part = blockIdx.y;
  const int koff = part ? 576 + (part - 1) * 512 : 0;
  const int kend = part ? 512 : 576;
  const half_t* Ap = A + koff;
  const half_t* Bp = B + koff;
  float* C = Cp + (size_t)part * M * N;

  const int R = M / 64, NT = N / 64;
  int b = blockIdx.x;
  int xcd = b & 7, q = b >> 3;
  int ct = q % NT, rg = q / NT;
  int r = rg * 8 + xcd;
  if (r >= R) return;

  const int tid = threadIdx.x;
  const int wave = tid >> 6, lane = tid & 63;
  const int wm = wave >> 1, wn = wave & 1;
  const int bm = r * 64, bn = ct * 64;

  const int rA = lane >> 2;
  const int swz = (rA & 3) ^ ((rA >> 2) & 3);
  const int cA = ((lane & 3) ^ swz) * 8;

  f32x4 acc[2][2];
  #pragma unroll
  for (int tm = 0; tm < 2; ++tm)
    #pragma unroll
    for (int tn = 0; tn < 2; ++tn) acc[tm][tn] = {0.f, 0.f, 0.f, 0.f};

  for (int k0 = 0; k0 < kend; k0 += 64) {
    #pragma unroll
    for (int p = 0; p < 2; ++p) {
      int kk = k0 + p * 32;
      int row = wave * 16;
      gl2lds16(Ap + (size_t)(bm + row + rA) * SA + kk + cA,
               A_s + p * 64 * 32 + row * 32);
      gl2lds16(Bp + (size_t)(bn + row + rA) * SA + kk + cA,
               B_s + p * 64 * 32 + row * 32);
    }
    __syncthreads();
    const int fr = lane & 15;
    const int fs = (fr & 3) ^ ((fr >> 2) & 3);
    const int fk = ((lane >> 4) ^ fs) * 8;
    #pragma unroll
    for (int p = 0; p < 2; ++p) {
      const int pA = p * 64 * 32, pB = p * 64 * 32;
      halfx8 af[2], bf[2];
      #pragma unroll
      for (int tm = 0; tm < 2; ++tm) {
        int rr = (wm * 2 + tm) * 16 + fr;
        af[tm] = *(const halfx8*)(A_s + pA + rr * 32 + fk);
      }
      #pragma unroll
      for (int tn = 0; tn < 2; ++tn) {
        int rr = (wn * 2 + tn) * 16 + fr;
        bf[tn] = *(const halfx8*)(B_s + pB + rr * 32 + fk);
      }
      #pragma unroll
      for (int tm = 0; tm < 2; ++tm)
        #pragma unroll
        for (int tn = 0; tn < 2; ++tn)
          acc[tm][tn] = __builtin_amdgcn_mfma_f32_16x16x32_f16(af[tm], bf[tn], acc[tm][tn], 0, 0, 0);
    }
    __syncthreads();
  }

  const int col0 = lane & 15, rq = (lane >> 4) * 4;
  #pragma unroll
  for (int tm = 0; tm < 2; ++tm)
    #pragma unroll
    for (int tn = 0; tn < 2; ++tn) {
      int col = bn + (wn * 2 + tn) * 16 + col0;
      float badd = (part == 0) ? (bias1[col] + bias2[col]) : 0.f;
      #pragma unroll
      for (int rr = 0; rr < 4; ++rr) {
        int row = bm + (wm * 2 + tm) * 16 + rq + rr;
        C[(size_t)row * N + col] = acc[tm][tn][rr] + badd;
      }
    }
}

// ============================================================
// GAT layer 2, 512 threads (8 waves). Round-26: stage the graph's full
// xlr panel (33x1024 fp16 = 67.6 KB) into LDS once with coalesced halfx8
// loads; logits AND aggregation then read LDS. Fixes the aggregation's
// stride-64 scalar fp16 global loads (8 per (n,e), L2-latency-bound) and
// the logits' repeated global row reads. Aggregation LDS reads are
// lane-consecutive 16-bit -> 2 lanes/bank = conflict-free (m136).
// ============================================================
__global__ __launch_bounds__(512) void gat2_kernel(
    const half_t* __restrict__ xlr, const int* __restrict__ src, const int* __restrict__ dst,
    const float* __restrict__ ea, const float* __restrict__ We,
    const float* __restrict__ att, const float* __restrict__ bias,
    half_t* __restrict__ h2, int g0) {
  __shared__ alignas(16) half_t xl_s[N_NODES * 1024];   // 67.6 KB
  __shared__ alignas(16) float We_s[3 * 512];
  __shared__ alignas(16) float att_s[512];
  __shared__ float b_s[HID];
  __shared__ float easX[EPG], easY[EPG], easZ[EPG];
  __shared__ float logit_s[HEADS * 65];
  __shared__ int sloc[EPG], dloc[EPG], deg[N_NODES], start[N_NODES], fill[N_NODES], elist[EPG];

  const int g = g0 + blockIdx.x, tid = threadIdx.x;
  const int nb = g * N_NODES, eb = g * EPG;
  const int lb = blockIdx.x * N_NODES;
  const int wave = tid >> 6, lane = tid & 63;

  // stage xlr panel: 33 rows x 128 halfx8 chunks = 4224 vector copies
  {
    const halfx8* srcp = (const halfx8*)(xlr + (size_t)lb * 1024);
    halfx8* dstp = (halfx8*)xl_s;
    for (int i = tid; i < N_NODES * 128; i += 512) dstp[i] = srcp[i];
  }

  for (int i = tid; i < 1536; i += 512) We_s[i] = We[i];
  if (tid < 512) att_s[tid] = att[tid];
  if (tid < HID) b_s[tid] = bias[tid];
  if (tid < EPG) {
    easX[tid] = ea[(eb + tid) * 3 + 0];
    easY[tid] = ea[(eb + tid) * 3 + 1];
    easZ[tid] = ea[(eb + tid) * 3 + 2];
    sloc[tid] = src[eb + tid] - nb;
    dloc[tid] = dst[eb + tid] - nb;
  }
  if (tid < N_NODES) { deg[tid] = 0; fill[tid] = 0; }
  __syncthreads();
  if (tid < EPG) atomicAdd(&deg[dloc[tid]], 1);
  __syncthreads();
  if (tid == 0) { int a = 0; for (int n = 0; n < N_NODES; ++n) { start[n] = a; a += deg[n]; } }
  __syncthreads();
  if (tid < EPG) { int d = dloc[tid]; int p = atomicAdd(&fill[d], 1); elist[start[d] + p] = tid; }
  __syncthreads();

  const int j0 = lane * 8;
  float w0[8], w1[8], w2[8], at8[8];
  #pragma unroll
  for (int q = 0; q < 8; ++q) {
    w0[q] = We_s[j0 + q];
    w1[q] = We_s[512 + j0 + q];
    w2[q] = We_s[1024 + j0 + q];
    at8[q] = att_s[j0 + q];
  }

  // logits: one wave per edge (8 iterations at 8 waves), panel from LDS
  for (int e = wave; e < EPG; e += 8) {
    int s = sloc[e], d = dloc[e];
    halfx8 xlv = *((const halfx8*)(xl_s + (size_t)s * 1024) + lane);
    halfx8 xrv = *((const halfx8*)(xl_s + (size_t)d * 1024 + 512) + lane);
    float e0 = easX[e], e1 = easY[e], e2 = easZ[e];
    float acc = 0.f;
    #pragma unroll
    for (int q = 0; q < 8; ++q) {
      float v = (float)xlv[q] + (float)xrv[q] + e0 * w0[q] + e1 * w1[q] + e2 * w2[q];
      acc += lreluf_(v) * at8[q];
    }
    acc += __shfl_xor(acc, 1, 64);
    acc += __shfl_xor(acc, 2, 64);
    acc += __shfl_xor(acc, 4, 64);
    if ((lane & 7) == 0) logit_s[(lane >> 3) * 65 + e] = acc;
  }
  __syncthreads();

  // softmax: one pass, h = tid>>6, n = lane (skip n>=33); exp deduped
  {
    int h = tid >> 6, n = tid & 63;
    if (n < N_NODES) {
      int s0 = start[n], dn = deg[n];
      float mx = -1e30f;
      for (int i = 0; i < dn; ++i) mx = fmaxf(mx, logit_s[h * 65 + elist[s0 + i]]);
      float den = 0.f;
      for (int i = 0; i < dn; ++i) {
        int e = elist[s0 + i];
        float ex = __expf(logit_s[h * 65 + e] - mx);
        logit_s[h * 65 + e] = ex;
        den += ex;
      }
      float inv = 1.f / (den + 1e-16f);
      for (int i = 0; i < dn; ++i) logit_s[h * 65 + elist[s0 + i]] *= inv;
    }
  }
  __syncthreads();

  // aggregation: wave-task n (5 iterations at 8 waves), lane = HID channel;
  // xl rows served from LDS (lane-consecutive u16 reads, conflict-free)
  for (int n = wave; n < N_NODES; n += 8) {
    float acc = 0.f;
    int s0 = start[n], dn = deg[n];
    for (int i = 0; i < dn; ++i) {
      int e = elist[s0 + i], s = sloc[e];
      const half_t* row = xl_s + (size_t)s * 1024 + lane;
      #pragma unroll
      for (int h = 0; h < 8; ++h)
        acc += logit_s[h * 65 + e] * (float)row[h * 64];
    }
    float v = eluf_(acc * 0.125f + b_s[lane]);
    h2[(size_t)(nb + n) * HID + lane] = (half_t)v;
  }
}

// ============================================================
// Fused LSTM1 + x2 + LSTM2 + FC — round-23/25 (verified): fp16 weights
// resident in registers, matvec via v_dot2_f32_f16, fast gate
// transcendentals on the 48-step serial critical path.
// ============================================================
__global__ __launch_bounds__(512) void lstm_all(
    const float* __restrict__ X0, const float* __restrict__ X1,
    const float* __restrict__ X2p, const float* __restrict__ X3,
    const float* __restrict__ Whh1,
    const float* __restrict__ Wih2, const float* __restrict__ bih2,
    const float* __restrict__ bhh2, const float* __restrict__ Whh2,
    const float* __restrict__ fcW, const float* __restrict__ fcb,
    float* __restrict__ out) {
  __shared__ alignas(16) _Float16 hs1h[LSTM1_H];        // h1 as fp16
  __shared__ float cs1[LSTM1_H], gs1[512];
  __shared__ alignas(16) _Float16 Y1h[SEQ][LSTM1_H];    // 6 KB
  __shared__ alignas(16) _Float16 hs2h[LSTM2_H];
  __shared__ float hs2f[LSTM2_H], cs2[LSTM2_H], gs2[256];
  const int tid = threadIdx.x, b = blockIdx.x;

  // convert Whh1 row tid -> 64 half2 in regs (64 VGPRs; fits sub-128 cap)
  half2_t w1[64];
  {
    const float4* wp = (const float4*)(Whh1 + (size_t)tid * LSTM1_H);
    #pragma unroll
    for (int q = 0; q < 32; ++q) {
      float4 v = wp[q];
      w1[2 * q]     = half2_t{(_Float16)v.x, (_Float16)v.y};
      w1[2 * q + 1] = half2_t{(_Float16)v.z, (_Float16)v.w};
    }
  }
  if (tid < LSTM1_H) { hs1h[tid] = (_Float16)0.f; cs1[tid] = 0.f; }

  // prefetch X(0)
  const size_t xbase = (size_t)b * SEQ * 512 + tid;
  float xn0 = X0[xbase], xn1 = X1[xbase], xn2 = X2p[xbase], xn3 = X3[xbase];
  __syncthreads();

  for (int t = 0; t < SEQ; ++t) {
    // matvec: 16 broadcast LDS b128 reads + 64 fdot2 (4 indep chains)
    float a0 = 0.f, a1 = 0.f, a2 = 0.f, a3 = 0.f;
    #pragma unroll
    for (int q = 0; q < 16; ++q) {
      halfx8 hh = *(const halfx8*)(hs1h + q * 8);
      half2_t p0 = {hh[0], hh[1]}, p1 = {hh[2], hh[3]};
      half2_t p2 = {hh[4], hh[5]}, p3 = {hh[6], hh[7]};
      a0 = __builtin_amdgcn_fdot2(w1[q * 4 + 0], p0, a0, false);
      a1 = __builtin_amdgcn_fdot2(w1[q * 4 + 1], p1, a1, false);
      a2 = __builtin_amdgcn_fdot2(w1[q * 4 + 2], p2, a2, false);
      a3 = __builtin_amdgcn_fdot2(w1[q * 4 + 3], p3, a3, false);
    }
    float g = (a0 + a1) + (a2 + a3) + ((xn0 + xn1) + (xn2 + xn3));
    if (t + 1 < SEQ) {
      size_t xo = xbase + (size_t)(t + 1) * 512;
      xn0 = X0[xo]; xn1 = X1[xo]; xn2 = X2p[xo]; xn3 = X3[xo];
    }
    gs1[tid] = g;
    __syncthreads();
    if (tid < LSTM1_H) {
      float ig = sigmoidf_(gs1[tid]);
      float fg = sigmoidf_(gs1[LSTM1_H + tid]);
      float gg = tanhf_(gs1[2 * LSTM1_H + tid]);
      float og = sigmoidf_(gs1[3 * LSTM1_H + tid]);
      float c = fg * cs1[tid] + ig * gg;
      cs1[tid] = c;
      float h = og * tanhf_(c);
      _Float16 hh_ = (_Float16)h;
      hs1h[tid] = hh_;
      Y1h[t][tid] = hh_;
    }
    __syncthreads();
  }

  // ---- LSTM2: 256 threads own full rows as fp16 (96 VGPRs) ----
  half2_t w2x[64], w2h[32];
  float bb2 = 0.f;
  if (tid < 256) {
    const float4* wxp = (const float4*)(Wih2 + (size_t)tid * LSTM1_H);
    #pragma unroll
    for (int q = 0; q < 32; ++q) {
      float4 v = wxp[q];
      w2x[2 * q]     = half2_t{(_Float16)v.x, (_Float16)v.y};
      w2x[2 * q + 1] = half2_t{(_Float16)v.z, (_Float16)v.w};
    }
    const float4* whp = (const float4*)(Whh2 + (size_t)tid * LSTM2_H);
    #pragma unroll
    for (int q = 0; q < 16; ++q) {
      float4 v = whp[q];
      w2h[2 * q]     = half2_t{(_Float16)v.x, (_Float16)v.y};
      w2h[2 * q + 1] = half2_t{(_Float16)v.z, (_Float16)v.w};
    }
    bb2 = bih2[tid] + bhh2[tid];
  }
  if (tid < LSTM2_H) { hs2h[tid] = (_Float16)0.f; hs2f[tid] = 0.f; cs2[tid] = 0.f; }
  __syncthreads();

  for (int t = 0; t < SEQ; ++t) {
    if (tid < 256) {
      const _Float16* y = Y1h[t];
      float a0 = 0.f, a1 = 0.f, a2 = 0.f, a3 = 0.f;
      #pragma unroll
      for (int q = 0; q < 16; ++q) {
        halfx8 yy = *(const halfx8*)(y + q * 8);
        half2_t p0 = {yy[0], yy[1]}, p1 = {yy[2], yy[3]};
        half2_t p2 = {yy[4], yy[5]}, p3 = {yy[6], yy[7]};
        a0 = __builtin_amdgcn_fdot2(w2x[q * 4 + 0], p0, a0, false);
        a1 = __builtin_amdgcn_fdot2(w2x[q * 4 + 1], p1, a1, false);
        a2 = __builtin_amdgcn_fdot2(w2x[q * 4 + 2], p2, a2, false);
        a3 = __builtin_amdgcn_fdot2(w2x[q * 4 + 3], p3, a3, false);
      }
      #pragma unroll
      for (int q = 0; q < 8; ++q) {
        halfx8 hh = *(const halfx8*)(hs2h + q * 8);
        half2_t p0 = {hh[0], hh[1]}, p1 = {hh[2], hh[3]};
        half2_t p2 = {hh[4], hh[5]}, p3 = {hh[6], hh[7]};
        a0 = __builtin_amdgcn_fdot2(w2h[q * 4 + 0], p0, a0, false);
        a1 = __builtin_amdgcn_fdot2(w2h[q * 4 + 1], p1, a1, false);
        a2 = __builtin_amdgcn_fdot2(w2h[q * 4 + 2], p2, a2, false);
        a3 = __builtin_amdgcn_fdot2(w2h[q * 4 + 3], p3, a3, false);
      }
      gs2[tid] = (a0 + a1) + (a2 + a3) + bb2;
    }
    __syncthreads();
    if (tid < LSTM2_H) {
      float ig = sigmoidf_(gs2[tid]);
      float fg = sigmoidf_(gs2[LSTM2_H + tid]);
      float gg = tanhf_(gs2[2 * LSTM2_H + tid]);
      float og = sigmoidf_(gs2[3 * LSTM2_H + tid]);
      float c = fg * cs2[tid] + ig * gg;
      cs2[tid] = c;
      float h = og * tanhf_(c);
      hs2h[tid] = (_Float16)h;
      hs2f[tid] = h;
    }
    __syncthreads();
  }

  if (tid < 4) {
    float acc = fcb[tid];
    #pragma unroll
    for (int k = 0; k < LSTM2_H; ++k) acc += fcW[tid * LSTM2_H + k] * hs2f[k];
    out[b * 4 + tid] = acc;
  }
}

// ============================================================
extern "C" void kernel_launch(void* const* d_in, const int* in_sizes, int n_in,
                              void* d_out, int out_size, void* d_ws, size_t ws_size,
                              hipStream_t stream) {
  const float* x       = (const float*)d_in[0];
  const int*   eidx    = (const int*)d_in[1];
  const float* eattr   = (const float*)d_in[2];
  const float* g1_Wl   = (const float*)d_in[3];
  const float* g1_Wr   = (const float*)d_in[4];
  const float* g1_We   = (const float*)d_in[5];
  const float* g1_att  = (const float*)d_in[6];
  const float* g1_b    = (const float*)d_in[7];
  const float* g2_Wl   = (const float*)d_in[8];
  const float* g2_Wr   = (const float*)d_in[9];
  const float* g2_We   = (const float*)d_in[10];
  const float* g2_att  = (const float*)d_in[11];
  const float* g2_b    = (const float*)d_in[12];
  const float* l1_Wih  = (const float*)d_in[13];
  const float* l1_Whh  = (const float*)d_in[14];
  const float* l1_bih  = (const float*)d_in[15];
  const float* l1_bhh  = (const float*)d_in[16];
  const float* l2_Wih  = (const float*)d_in[17];
  const float* l2_Whh  = (const float*)d_in[18];
  const float* l2_bih  = (const float*)d_in[19];
  const float* l2_bhh  = (const float*)d_in[20];
  const float* fc_W    = (const float*)d_in[21];
  const float* fc_b    = (const float*)d_in[22];
  float* out = (float*)d_out;

  const int* src = eidx;
  const int* dst = eidx + E_EDGES;

  // ---- runtime-adaptive chunking (all chunk_n divisible by 128) ----
  const int cand[4] = {1, 2, 3, 6};
  int nchunks = 0;
  half_t *h1 = nullptr, *xlr2c = nullptr, *h2 = nullptr, *B2 = nullptr, *W1f = nullptr;
  float *X1p = nullptr;
  int chunk_g = 0, chunk_n = 0;
  for (int ci = 0; ci < 4; ++ci) {
    int C = cand[ci];
    int CG = G_GRAPHS / C, CN = CG * N_NODES;
    char* p = (char*)d_ws;
    auto alloc = [&](size_t bytes) { char* r = p; p += (bytes + 255) & ~(size_t)255; return r; };
    half_t* t_h1    = (half_t*)alloc((size_t)CN * HC * 2);
    half_t* t_xlr2c = (half_t*)alloc((size_t)CN * 1024 * 2);
    half_t* t_h2    = (half_t*)alloc((size_t)G_GRAPHS * 2112 * 2);
    half_t* t_B2    = (half_t*)alloc((size_t)1024 * 512 * 2);
    half_t* t_W1f   = (half_t*)alloc((size_t)512 * 2112 * 2);
    float*  t_X1p   = (float*)alloc((size_t)4 * G_GRAPHS * 512 * 4);
    if ((size_t)(p - (char*)d_ws) <= ws_size) {
      nchunks = C; chunk_g = CG; chunk_n = CN;
      h1 = t_h1; xlr2c = t_xlr2c; h2 = t_h2; B2 = t_B2; W1f = t_W1f;
      X1p = t_X1p;
      break;
    }
  }
  if (nchunks == 0) return;   // guard: zero output instead of memory fault

  for (int c = 0; c < nchunks; ++c) {
    int g0 = c * chunk_g;
    int extra = (c == 0) ? CONV_BLOCKS : 0;
    gat1_kernel<<<chunk_g + extra, 512, 0, stream>>>(
        x, src, dst, eattr, g1_Wl, g1_Wr, g1_We, g1_att, g1_b, h1, g0, chunk_g,
        g2_Wl, g2_Wr, B2, l1_Wih, W1f);
    int gblocks = (chunk_n / 128) * 8;    // % 8 == 0 for all chunk candidates
    gemm_m97<<<gblocks, 256, 0, stream>>>(h1, B2, xlr2c, chunk_n);
    gat2_kernel<<<chunk_g, 512, 0, stream>>>(xlr2c, src, dst, eattr, g2_We,
                                             g2_att, g2_b, h2, g0);
  }

  // X1 partials = h2 @ l1_Wih^T (+biases in part 0), split-K=4, one dispatch
  {
    dim3 grid(192, 4);
    gemm_f16_splitk<<<grid, 256, 0, stream>>>(h2, W1f, X1p, l1_bih, l1_bhh,
                                              G_GRAPHS, 512);
  }

  // fused LSTM1 + x2 + LSTM2 + FC
  {
    size_t PS = (size_t)G_GRAPHS * 512;
    lstm_all<<<BATCH, 512, 0, stream>>>(X1p, X1p + PS, X1p + 2 * PS, X1p + 3 * PS,
                                        l1_Whh, l2_Wih, l2_bih, l2_bhh, l2_Whh,
                                        fc_W, fc_b, out);
  }
}

// Round 13
// 299.742 us; speedup vs baseline: 1.0502x; 1.0502x over previous
//
#include <hip/hip_runtime.h>
#include <math.h>

// ---- problem constants ----
#define N_NODES 33
#define SEQ 24
#define BATCH 64
#define G_GRAPHS (BATCH * SEQ)          // 1536
#define EPG 64
#define E_EDGES (G_GRAPHS * EPG)        // 98304
#define N_TOTAL (G_GRAPHS * N_NODES)    // 50688
#define HID 64
#define HEADS 8
#define HC (HID * HEADS)                // 512
#define LSTM1_H 128
#define LSTM2_H 64
#define N_CLASSES 4
#define NEG_SLOPE 0.2f
// conv fused into gat1 chunk 0: 128 transpose tiles + 264 W1f blocks
#define CONV_BLOCKS (128 + 264)

// ---- fast transcendentals (round-25, verified: gat1 74.7 -> <64us,
// absmax unchanged): v_exp_f32-based, ~2-3 insts vs ~15-20 libm.
__device__ __forceinline__ float sigmoidf_(float x) { return 1.f / (1.f + __expf(-x)); }
__device__ __forceinline__ float eluf_(float x) { return x > 0.f ? x : __expf(x) - 1.f; }
__device__ __forceinline__ float lreluf_(float x) { return x > 0.f ? x : NEG_SLOPE * x; }
__device__ __forceinline__ float tanhf_(float x) {
  float t = __expf(-2.f * fabsf(x));       // t in (0,1], no inf/NaN
  float r = (1.f - t) / (1.f + t);
  return x >= 0.f ? r : -r;
}

typedef __attribute__((ext_vector_type(4))) float f32x4;
typedef _Float16 half_t;
typedef __attribute__((ext_vector_type(8))) _Float16 halfx8;
typedef __attribute__((ext_vector_type(2))) _Float16 half2_t;

__device__ __forceinline__ void gl2lds16(const void* g, void* l) {
  __builtin_amdgcn_global_load_lds(
      (__attribute__((address_space(1))) const unsigned int*)g,
      (__attribute__((address_space(3))) unsigned int*)l, 16, 0, 0);
}

// ============================================================
// GAT layer 1, 512 threads (8 waves). Blocks >= gat_blocks do the one-time
// fp16 weight conversion: 128 LDS-transpose tiles + 264 elementwise W1f blocks.
// ============================================================
__global__ __launch_bounds__(512) void gat1_kernel(
    const float* __restrict__ x, const int* __restrict__ src, const int* __restrict__ dst,
    const float* __restrict__ ea, const float* __restrict__ Wl, const float* __restrict__ Wr,
    const float* __restrict__ We, const float* __restrict__ att, const float* __restrict__ bias,
    half_t* __restrict__ h1, int g0, int gat_blocks,
    const float* __restrict__ g2Wl, const float* __restrict__ g2Wr,
    half_t* __restrict__ B2, const float* __restrict__ W1, half_t* __restrict__ W1f) {
  const int tid = threadIdx.x;

  __shared__ alignas(16) float Wl_s[2 * 512];
  __shared__ alignas(16) float Wr_s[2 * 512];
  __shared__ alignas(16) float We_s[3 * 512];
  __shared__ alignas(16) float att_s[512];
  __shared__ float xs0_s[N_NODES + 1], xs1_s[N_NODES + 1];
  __shared__ float easX[EPG], easY[EPG], easZ[EPG];
  __shared__ float logit_s[HEADS * 65];
  __shared__ int sloc[EPG], dloc[EPG], deg[N_NODES], start[N_NODES], fill[N_NODES], elist[EPG];
  __shared__ float tr[64 * 65];          // transpose tile (conv path)

  if ((int)blockIdx.x >= gat_blocks) {
    int cb = blockIdx.x - gat_blocks;
    if (cb < 128) {
      // transpose B2[n][k] = [Wl|Wr][k][n], 64x64 tile, coalesced both ways
      int kt = cb & 7, nt = cb >> 3;
      int k0 = kt * 64, n0 = nt * 64;
      int r = tid >> 6, c = tid & 63;
      #pragma unroll
      for (int rr = 0; rr < 8; ++rr) {
        int kl = rr * 8 + r;
        int n = n0 + c;
        float v = (n < 512) ? g2Wl[(size_t)(k0 + kl) * 512 + n]
                            : g2Wr[(size_t)(k0 + kl) * 512 + n - 512];
        tr[kl * 65 + c] = v;
      }
      __syncthreads();
      #pragma unroll
      for (int rr = 0; rr < 8; ++rr) {
        int nl = rr * 8 + r;
        B2[(size_t)(n0 + nl) * 512 + k0 + c] = (half_t)tr[c * 65 + nl];
      }
    } else {
      int base = (cb - 128) * 4096 + tid;
      #pragma unroll
      for (int i = 0; i < 8; ++i) {
        int idx = base + i * 512;
        if (idx < 512 * 2112) W1f[idx] = (half_t)W1[idx];
      }
    }
    return;
  }

  const int g = g0 + blockIdx.x;
  const int nb = g * N_NODES, eb = g * EPG;
  const int lb = blockIdx.x * N_NODES;

  for (int i = tid; i < 1024; i += 512) { Wl_s[i] = Wl[i]; Wr_s[i] = Wr[i]; }
  for (int i = tid; i < 1536; i += 512) We_s[i] = We[i];
  if (tid < 512) att_s[tid] = att[tid];
  if (tid < 2 * N_NODES) {
    float v = x[nb * 2 + tid];
    if (tid & 1) xs1_s[tid >> 1] = v; else xs0_s[tid >> 1] = v;
  }
  if (tid < EPG) {
    easX[tid] = ea[(eb + tid) * 3 + 0];
    easY[tid] = ea[(eb + tid) * 3 + 1];
    easZ[tid] = ea[(eb + tid) * 3 + 2];
    sloc[tid] = src[eb + tid] - nb;
    dloc[tid] = dst[eb + tid] - nb;
  }
  if (tid < N_NODES) { deg[tid] = 0; fill[tid] = 0; }
  __syncthreads();
  if (tid < EPG) atomicAdd(&deg[dloc[tid]], 1);
  __syncthreads();
  if (tid == 0) { int a = 0; for (int n = 0; n < N_NODES; ++n) { start[n] = a; a += deg[n]; } }
  __syncthreads();
  if (tid < EPG) { int d = dloc[tid]; int p = atomicAdd(&fill[d], 1); elist[start[d] + p] = tid; }

  // logits: one pass, h = tid>>6 (wave-uniform), e = lane
  {
    int h = tid >> 6, e = tid & 63;
    int s = sloc[e], d = dloc[e];
    float xs0 = xs0_s[s], xs1 = xs1_s[s], xd0 = xs0_s[d], xd1 = xs1_s[d];
    float e0 = easX[e], e1 = easY[e], e2 = easZ[e];
    float acc = 0.f;
    int base = h * 64;
    #pragma unroll
    for (int c4 = 0; c4 < 16; ++c4) {
      int j = base + c4 * 4;
      f32x4 wl0 = *(const f32x4*)(Wl_s + j);
      f32x4 wl1 = *(const f32x4*)(Wl_s + 512 + j);
      f32x4 wr0 = *(const f32x4*)(Wr_s + j);
      f32x4 wr1 = *(const f32x4*)(Wr_s + 512 + j);
      f32x4 we0 = *(const f32x4*)(We_s + j);
      f32x4 we1 = *(const f32x4*)(We_s + 512 + j);
      f32x4 we2 = *(const f32x4*)(We_s + 1024 + j);
      f32x4 at  = *(const f32x4*)(att_s + j);
      #pragma unroll
      for (int q = 0; q < 4; ++q) {
        float v = xs0 * wl0[q] + xs1 * wl1[q]
                + xd0 * wr0[q] + xd1 * wr1[q]
                + e0 * we0[q] + e1 * we1[q] + e2 * we2[q];
        acc += lreluf_(v) * at[q];
      }
    }
    logit_s[h * 65 + e] = acc;
  }
  __syncthreads();

  // segment softmax: one pass, h = tid>>6, n = lane (skip n>=33); exp deduped
  {
    int h = tid >> 6, n = tid & 63;
    if (n < N_NODES) {
      int s0 = start[n], dn = deg[n];
      float mx = -1e30f;
      for (int i = 0; i < dn; ++i) mx = fmaxf(mx, logit_s[h * 65 + elist[s0 + i]]);
      float den = 0.f;
      for (int i = 0; i < dn; ++i) {
        int e = elist[s0 + i];
        float ex = __expf(logit_s[h * 65 + e] - mx);
        logit_s[h * 65 + e] = ex;
        den += ex;
      }
      float inv = 1.f / (den + 1e-16f);
      for (int i = 0; i < dn; ++i) logit_s[h * 65 + elist[s0 + i]] *= inv;
    }
  }
  __syncthreads();

  // aggregation: task = (n, 8-channel block); n = t>>6 wave-uniform, jb = lane
  for (int t = tid; t < N_NODES * 64; t += 512) {
    int n = t >> 6, jb = t & 63;
    int j0 = jb * 8, h = jb >> 3;
    f32x4 wa0 = *(const f32x4*)(Wl_s + j0);
    f32x4 wa1 = *(const f32x4*)(Wl_s + j0 + 4);
    f32x4 wb0 = *(const f32x4*)(Wl_s + 512 + j0);
    f32x4 wb1 = *(const f32x4*)(Wl_s + 512 + j0 + 4);
    float acc[8] = {};
    int s0 = start[n], dn = deg[n];
    for (int i = 0; i < dn; ++i) {
      int e = elist[s0 + i]; int s = sloc[e];
      float a = logit_s[h * 65 + e];
      float ax0 = a * xs0_s[s], ax1 = a * xs1_s[s];
      #pragma unroll
      for (int q = 0; q < 4; ++q) {
        acc[q]     += ax0 * wa0[q] + ax1 * wb0[q];
        acc[4 + q] += ax0 * wa1[q] + ax1 * wb1[q];
      }
    }
    f32x4 b0 = *(const f32x4*)(bias + j0);
    f32x4 b1 = *(const f32x4*)(bias + j0 + 4);
    halfx8 vh;
    #pragma unroll
    for (int cc = 0; cc < 8; ++cc) {
      float bb = (cc < 4) ? b0[cc] : b1[cc - 4];
      vh[cc] = (half_t)eluf_(acc[cc] + bb);
    }
    *(halfx8*)(h1 + (size_t)(lb + n) * HC + j0) = vh;
  }
}

// ============================================================
// Main GEMM (verified: ~64us, 832 TF = 95% of the m97 structure ceiling,
// FETCH 31.4MB, 0 bank conflicts). Round-9: work-stealing destroys XCD
// affinity (FETCH 5x). Rounds 1/2: deep pipelines worse at K=512. DONE.
// ============================================================
#define LDA8(S, rr, c) \
  (*(const halfx8*)((S) + (rr) * 64 + ((((c) ^ ((rr) & 7))) << 3)))

__global__ __launch_bounds__(256, 4) void gemm_m97(
    const half_t* __restrict__ A, const half_t* __restrict__ B,
    half_t* __restrict__ C, int M) {
  // staging: A 128x64 + B 128x64 halfs = 32 KB; C-bounce 128x132 = 33 KB
  __shared__ alignas(16) half_t lds[128 * 132];

  half_t* const As = lds;                // 8192 halfs
  half_t* const Bs = lds + 8192;         // 8192 halfs

  const int R = M >> 7;                  // row tiles
  const int nwg = R * 8;                 // 8 col tiles; nwg % 8 == 0
  const int cpx = nwg >> 3;
  const int bid = blockIdx.x;
  const int swz = (bid & 7) * cpx + (bid >> 3);  // bijective XCD swizzle
  const int ct = swz & 7, r = swz >> 3;          // ct fast: A-panel L2 reuse

  const int tid = threadIdx.x;
  const int wave = tid >> 6, lane = tid & 63;
  const int wm = wave >> 1, wn = wave & 1;       // 2x2 waves, 64x64 each
  const int bm = r << 7, bn = ct << 7;

  // staging: lane -> row rl of 8-row group, pre-swizzled global chunk
  const int rl = lane >> 3;
  const int gc = ((lane & 7) ^ rl) << 3;
  // fragment read: row fr in 16-row tile, k-quarter kq
  const int fr = lane & 15;
  const int kq = lane >> 4;

  f32x4 acc[4][4];
  #pragma unroll
  for (int tm = 0; tm < 4; ++tm)
    #pragma unroll
    for (int tn = 0; tn < 4; ++tn) acc[tm][tn] = {0.f, 0.f, 0.f, 0.f};

  for (int t = 0; t < 8; ++t) {
    // stage K-tile t: A 128x64 + B 128x64, 8 gl2lds16 per wave
    #pragma unroll
    for (int i = 0; i < 4; ++i) {
      int r0 = i * 32 + wave * 8;
      gl2lds16(A + (size_t)(bm + r0 + rl) * 512 + t * 64 + gc, As + r0 * 64);
    }
    #pragma unroll
    for (int i = 0; i < 4; ++i) {
      int r0 = i * 32 + wave * 8;
      gl2lds16(B + (size_t)(bn + r0 + rl) * 512 + t * 64 + gc, Bs + r0 * 64);
    }
    __syncthreads();   // compiler drains vmcnt before barrier

    #pragma unroll
    for (int ks = 0; ks < 2; ++ks) {
      halfx8 af[4], bf[4];
      #pragma unroll
      for (int tm = 0; tm < 4; ++tm)
        af[tm] = LDA8(As, wm * 64 + tm * 16 + fr, ks * 4 + kq);
      #pragma unroll
      for (int tn = 0; tn < 4; ++tn)
        bf[tn] = LDA8(Bs, wn * 64 + tn * 16 + fr, ks * 4 + kq);
      #pragma unroll
      for (int tm = 0; tm < 4; ++tm)
        #pragma unroll
        for (int tn = 0; tn < 4; ++tn)
          acc[tm][tn] = __builtin_amdgcn_mfma_f32_16x16x32_f16(
              af[tm], bf[tn], acc[tm][tn], 0, 0, 0);
    }
    __syncthreads();   // protect LDS overwrite next K-step
  }

  // epilogue: fp16 bounce through LDS (stride 132), coalesced halfx8 stores
  half_t* Cs = lds;
  const int rq4 = (lane >> 4) * 4;
  const int cl0 = lane & 15;
  #pragma unroll
  for (int tm = 0; tm < 4; ++tm)
    #pragma unroll
    for (int tn = 0; tn < 4; ++tn) {
      int cl = wn * 64 + tn * 16 + cl0;
      #pragma unroll
      for (int rr = 0; rr < 4; ++rr)
        Cs[(wm * 64 + tm * 16 + rq4 + rr) * 132 + cl] = (half_t)acc[tm][tn][rr];
    }
  __syncthreads();
  #pragma unroll
  for (int pass = 0; pass < 8; ++pass) {
    int row = pass * 16 + (tid >> 4);
    int col = (tid & 15) * 8;
    halfx8 v = *(const halfx8*)(Cs + row * 132 + col);
    *(halfx8*)(C + (size_t)(bm + row) * 1024 + bn + col) = v;
  }
}

// ============================================================
// final GEMM, split-K=4 in one dispatch (round-14 verified)
// ============================================================
__global__ __launch_bounds__(256) void gemm_f16_splitk(
    const half_t* __restrict__ A, const half_t* __restrict__ B,
    float* __restrict__ Cp, const float* __restrict__ bias1, const float* __restrict__ bias2,
    int M, int N) {
  constexpr int SA = 2112;
  __shared__ half_t lds[(64 + 64) * 64];
  half_t* A_s = lds;
  half_t* B_s = A_s + 2 * 64 * 32;

  const int part = blockIdx.y;
  const int koff = part ? 576 + (part - 1) * 512 : 0;
  const int kend = part ? 512 : 576;
  const half_t* Ap = A + koff;
  const half_t* Bp = B + koff;
  float* C = Cp + (size_t)part * M * N;

  const int R = M / 64, NT = N / 64;
  int b = blockIdx.x;
  int xcd = b & 7, q = b >> 3;
  int ct = q % NT, rg = q / NT;
  int r = rg * 8 + xcd;
  if (r >= R) return;

  const int tid = threadIdx.x;
  const int wave = tid >> 6, lane = tid & 63;
  const int wm = wave >> 1, wn = wave & 1;
  const int bm = r * 64, bn = ct * 64;

  const int rA = lane >> 2;
  const int swz = (rA & 3) ^ ((rA >> 2) & 3);
  const int cA = ((lane & 3) ^ swz) * 8;

  f32x4 acc[2][2];
  #pragma unroll
  for (int tm = 0; tm < 2; ++tm)
    #pragma unroll
    for (int tn = 0; tn < 2; ++tn) acc[tm][tn] = {0.f, 0.f, 0.f, 0.f};

  for (int k0 = 0; k0 < kend; k0 += 64) {
    #pragma unroll
    for (int p = 0; p < 2; ++p) {
      int kk = k0 + p * 32;
      int row = wave * 16;
      gl2lds16(Ap + (size_t)(bm + row + rA) * SA + kk + cA,
               A_s + p * 64 * 32 + row * 32);
      gl2lds16(Bp + (size_t)(bn + row + rA) * SA + kk + cA,
               B_s + p * 64 * 32 + row * 32);
    }
    __syncthreads();
    const int fr = lane & 15;
    const int fs = (fr & 3) ^ ((fr >> 2) & 3);
    const int fk = ((lane >> 4) ^ fs) * 8;
    #pragma unroll
    for (int p = 0; p < 2; ++p) {
      const int pA = p * 64 * 32, pB = p * 64 * 32;
      halfx8 af[2], bf[2];
      #pragma unroll
      for (int tm = 0; tm < 2; ++tm) {
        int rr = (wm * 2 + tm) * 16 + fr;
        af[tm] = *(const halfx8*)(A_s + pA + rr * 32 + fk);
      }
      #pragma unroll
      for (int tn = 0; tn < 2; ++tn) {
        int rr = (wn * 2 + tn) * 16 + fr;
        bf[tn] = *(const halfx8*)(B_s + pB + rr * 32 + fk);
      }
      #pragma unroll
      for (int tm = 0; tm < 2; ++tm)
        #pragma unroll
        for (int tn = 0; tn < 2; ++tn)
          acc[tm][tn] = __builtin_amdgcn_mfma_f32_16x16x32_f16(af[tm], bf[tn], acc[tm][tn], 0, 0, 0);
    }
    __syncthreads();
  }

  const int col0 = lane & 15, rq = (lane >> 4) * 4;
  #pragma unroll
  for (int tm = 0; tm < 2; ++tm)
    #pragma unroll
    for (int tn = 0; tn < 2; ++tn) {
      int col = bn + (wn * 2 + tn) * 16 + col0;
      float badd = (part == 0) ? (bias1[col] + bias2[col]) : 0.f;
      #pragma unroll
      for (int rr = 0; rr < 4; ++rr) {
        int row = bm + (wm * 2 + tm) * 16 + rq + rr;
        C[(size_t)row * N + col] = acc[tm][tn][rr] + badd;
      }
    }
}

// ============================================================
// GAT layer 2, 512 threads (8 waves) — round-11 verified version.
// ROUND-12 LESSON: staging the 67.6KB xlr panel into LDS regressed
// (+8us): panel is L2-resident (FETCH ~4.6MB << footprint) and the
// staging pushed LDS to ~89KB -> 1 block/CU (was ~4). Don't stage
// cache-fitting data (Common-mistake #7).
// ============================================================
__global__ __launch_bounds__(512) void gat2_kernel(
    const half_t* __restrict__ xlr, const int* __restrict__ src, const int* __restrict__ dst,
    const float* __restrict__ ea, const float* __restrict__ We,
    const float* __restrict__ att, const float* __restrict__ bias,
    half_t* __restrict__ h2, int g0) {
  __shared__ alignas(16) float We_s[3 * 512];
  __shared__ alignas(16) float att_s[512];
  __shared__ float b_s[HID];
  __shared__ float easX[EPG], easY[EPG], easZ[EPG];
  __shared__ float logit_s[HEADS * 65];
  __shared__ int sloc[EPG], dloc[EPG], deg[N_NODES], start[N_NODES], fill[N_NODES], elist[EPG];

  const int g = g0 + blockIdx.x, tid = threadIdx.x;
  const int nb = g * N_NODES, eb = g * EPG;
  const int lb = blockIdx.x * N_NODES;
  const int wave = tid >> 6, lane = tid & 63;

  for (int i = tid; i < 1536; i += 512) We_s[i] = We[i];
  if (tid < 512) att_s[tid] = att[tid];
  if (tid < HID) b_s[tid] = bias[tid];
  if (tid < EPG) {
    easX[tid] = ea[(eb + tid) * 3 + 0];
    easY[tid] = ea[(eb + tid) * 3 + 1];
    easZ[tid] = ea[(eb + tid) * 3 + 2];
    sloc[tid] = src[eb + tid] - nb;
    dloc[tid] = dst[eb + tid] - nb;
  }
  if (tid < N_NODES) { deg[tid] = 0; fill[tid] = 0; }
  __syncthreads();
  if (tid < EPG) atomicAdd(&deg[dloc[tid]], 1);
  __syncthreads();
  if (tid == 0) { int a = 0; for (int n = 0; n < N_NODES; ++n) { start[n] = a; a += deg[n]; } }
  __syncthreads();
  if (tid < EPG) { int d = dloc[tid]; int p = atomicAdd(&fill[d], 1); elist[start[d] + p] = tid; }
  __syncthreads();

  const int j0 = lane * 8;
  float w0[8], w1[8], w2[8], at8[8];
  #pragma unroll
  for (int q = 0; q < 8; ++q) {
    w0[q] = We_s[j0 + q];
    w1[q] = We_s[512 + j0 + q];
    w2[q] = We_s[1024 + j0 + q];
    at8[q] = att_s[j0 + q];
  }

  // logits: one wave per edge (8 iterations at 8 waves)
  for (int e = wave; e < EPG; e += 8) {
    int s = sloc[e], d = dloc[e];
    halfx8 xlv = *((const halfx8*)(xlr + (size_t)(lb + s) * 1024) + lane);
    halfx8 xrv = *((const halfx8*)(xlr + (size_t)(lb + d) * 1024 + 512) + lane);
    float e0 = easX[e], e1 = easY[e], e2 = easZ[e];
    float acc = 0.f;
    #pragma unroll
    for (int q = 0; q < 8; ++q) {
      float v = (float)xlv[q] + (float)xrv[q] + e0 * w0[q] + e1 * w1[q] + e2 * w2[q];
      acc += lreluf_(v) * at8[q];
    }
    acc += __shfl_xor(acc, 1, 64);
    acc += __shfl_xor(acc, 2, 64);
    acc += __shfl_xor(acc, 4, 64);
    if ((lane & 7) == 0) logit_s[(lane >> 3) * 65 + e] = acc;
  }
  __syncthreads();

  // softmax: one pass, h = tid>>6, n = lane (skip n>=33); exp deduped
  {
    int h = tid >> 6, n = tid & 63;
    if (n < N_NODES) {
      int s0 = start[n], dn = deg[n];
      float mx = -1e30f;
      for (int i = 0; i < dn; ++i) mx = fmaxf(mx, logit_s[h * 65 + elist[s0 + i]]);
      float den = 0.f;
      for (int i = 0; i < dn; ++i) {
        int e = elist[s0 + i];
        float ex = __expf(logit_s[h * 65 + e] - mx);
        logit_s[h * 65 + e] = ex;
        den += ex;
      }
      float inv = 1.f / (den + 1e-16f);
      for (int i = 0; i < dn; ++i) logit_s[h * 65 + elist[s0 + i]] *= inv;
    }
  }
  __syncthreads();

  // aggregation: wave-task n (5 iterations at 8 waves), lane = HID channel
  for (int n = wave; n < N_NODES; n += 8) {
    float acc = 0.f;
    int s0 = start[n], dn = deg[n];
    for (int i = 0; i < dn; ++i) {
      int e = elist[s0 + i], s = sloc[e];
      const half_t* row = xlr + (size_t)(lb + s) * 1024 + lane;
      #pragma unroll
      for (int h = 0; h < 8; ++h)
        acc += logit_s[h * 65 + e] * (float)row[h * 64];
    }
    float v = eluf_(acc * 0.125f + b_s[lane]);
    h2[(size_t)(nb + n) * HID + lane] = (half_t)v;
  }
}

// ============================================================
// Fused LSTM1 + x2 + LSTM2 + FC — round-23/25 (verified): fp16 weights
// resident in registers, matvec via v_dot2_f32_f16, fast gate
// transcendentals on the 48-step serial critical path.
// ============================================================
__global__ __launch_bounds__(512) void lstm_all(
    const float* __restrict__ X0, const float* __restrict__ X1,
    const float* __restrict__ X2p, const float* __restrict__ X3,
    const float* __restrict__ Whh1,
    const float* __restrict__ Wih2, const float* __restrict__ bih2,
    const float* __restrict__ bhh2, const float* __restrict__ Whh2,
    const float* __restrict__ fcW, const float* __restrict__ fcb,
    float* __restrict__ out) {
  __shared__ alignas(16) _Float16 hs1h[LSTM1_H];        // h1 as fp16
  __shared__ float cs1[LSTM1_H], gs1[512];
  __shared__ alignas(16) _Float16 Y1h[SEQ][LSTM1_H];    // 6 KB
  __shared__ alignas(16) _Float16 hs2h[LSTM2_H];
  __shared__ float hs2f[LSTM2_H], cs2[LSTM2_H], gs2[256];
  const int tid = threadIdx.x, b = blockIdx.x;

  // convert Whh1 row tid -> 64 half2 in regs (64 VGPRs; fits sub-128 cap)
  half2_t w1[64];
  {
    const float4* wp = (const float4*)(Whh1 + (size_t)tid * LSTM1_H);
    #pragma unroll
    for (int q = 0; q < 32; ++q) {
      float4 v = wp[q];
      w1[2 * q]     = half2_t{(_Float16)v.x, (_Float16)v.y};
      w1[2 * q + 1] = half2_t{(_Float16)v.z, (_Float16)v.w};
    }
  }
  if (tid < LSTM1_H) { hs1h[tid] = (_Float16)0.f; cs1[tid] = 0.f; }

  // prefetch X(0)
  const size_t xbase = (size_t)b * SEQ * 512 + tid;
  float xn0 = X0[xbase], xn1 = X1[xbase], xn2 = X2p[xbase], xn3 = X3[xbase];
  __syncthreads();

  for (int t = 0; t < SEQ; ++t) {
    // matvec: 16 broadcast LDS b128 reads + 64 fdot2 (4 indep chains)
    float a0 = 0.f, a1 = 0.f, a2 = 0.f, a3 = 0.f;
    #pragma unroll
    for (int q = 0; q < 16; ++q) {
      halfx8 hh = *(const halfx8*)(hs1h + q * 8);
      half2_t p0 = {hh[0], hh[1]}, p1 = {hh[2], hh[3]};
      half2_t p2 = {hh[4], hh[5]}, p3 = {hh[6], hh[7]};
      a0 = __builtin_amdgcn_fdot2(w1[q * 4 + 0], p0, a0, false);
      a1 = __builtin_amdgcn_fdot2(w1[q * 4 + 1], p1, a1, false);
      a2 = __builtin_amdgcn_fdot2(w1[q * 4 + 2], p2, a2, false);
      a3 = __builtin_amdgcn_fdot2(w1[q * 4 + 3], p3, a3, false);
    }
    float g = (a0 + a1) + (a2 + a3) + ((xn0 + xn1) + (xn2 + xn3));
    if (t + 1 < SEQ) {
      size_t xo = xbase + (size_t)(t + 1) * 512;
      xn0 = X0[xo]; xn1 = X1[xo]; xn2 = X2p[xo]; xn3 = X3[xo];
    }
    gs1[tid] = g;
    __syncthreads();
    if (tid < LSTM1_H) {
      float ig = sigmoidf_(gs1[tid]);
      float fg = sigmoidf_(gs1[LSTM1_H + tid]);
      float gg = tanhf_(gs1[2 * LSTM1_H + tid]);
      float og = sigmoidf_(gs1[3 * LSTM1_H + tid]);
      float c = fg * cs1[tid] + ig * gg;
      cs1[tid] = c;
      float h = og * tanhf_(c);
      _Float16 hh_ = (_Float16)h;
      hs1h[tid] = hh_;
      Y1h[t][tid] = hh_;
    }
    __syncthreads();
  }

  // ---- LSTM2: 256 threads own full rows as fp16 (96 VGPRs) ----
  half2_t w2x[64], w2h[32];
  float bb2 = 0.f;
  if (tid < 256) {
    const float4* wxp = (const float4*)(Wih2 + (size_t)tid * LSTM1_H);
    #pragma unroll
    for (int q = 0; q < 32; ++q) {
      float4 v = wxp[q];
      w2x[2 * q]     = half2_t{(_Float16)v.x, (_Float16)v.y};
      w2x[2 * q + 1] = half2_t{(_Float16)v.z, (_Float16)v.w};
    }
    const float4* whp = (const float4*)(Whh2 + (size_t)tid * LSTM2_H);
    #pragma unroll
    for (int q = 0; q < 16; ++q) {
      float4 v = whp[q];
      w2h[2 * q]     = half2_t{(_Float16)v.x, (_Float16)v.y};
      w2h[2 * q + 1] = half2_t{(_Float16)v.z, (_Float16)v.w};
    }
    bb2 = bih2[tid] + bhh2[tid];
  }
  if (tid < LSTM2_H) { hs2h[tid] = (_Float16)0.f; hs2f[tid] = 0.f; cs2[tid] = 0.f; }
  __syncthreads();

  for (int t = 0; t < SEQ; ++t) {
    if (tid < 256) {
      const _Float16* y = Y1h[t];
      float a0 = 0.f, a1 = 0.f, a2 = 0.f, a3 = 0.f;
      #pragma unroll
      for (int q = 0; q < 16; ++q) {
        halfx8 yy = *(const halfx8*)(y + q * 8);
        half2_t p0 = {yy[0], yy[1]}, p1 = {yy[2], yy[3]};
        half2_t p2 = {yy[4], yy[5]}, p3 = {yy[6], yy[7]};
        a0 = __builtin_amdgcn_fdot2(w2x[q * 4 + 0], p0, a0, false);
        a1 = __builtin_amdgcn_fdot2(w2x[q * 4 + 1], p1, a1, false);
        a2 = __builtin_amdgcn_fdot2(w2x[q * 4 + 2], p2, a2, false);
        a3 = __builtin_amdgcn_fdot2(w2x[q * 4 + 3], p3, a3, false);
      }
      #pragma unroll
      for (int q = 0; q < 8; ++q) {
        halfx8 hh = *(const halfx8*)(hs2h + q * 8);
        half2_t p0 = {hh[0], hh[1]}, p1 = {hh[2], hh[3]};
        half2_t p2 = {hh[4], hh[5]}, p3 = {hh[6], hh[7]};
        a0 = __builtin_amdgcn_fdot2(w2h[q * 4 + 0], p0, a0, false);
        a1 = __builtin_amdgcn_fdot2(w2h[q * 4 + 1], p1, a1, false);
        a2 = __builtin_amdgcn_fdot2(w2h[q * 4 + 2], p2, a2, false);
        a3 = __builtin_amdgcn_fdot2(w2h[q * 4 + 3], p3, a3, false);
      }
      gs2[tid] = (a0 + a1) + (a2 + a3) + bb2;
    }
    __syncthreads();
    if (tid < LSTM2_H) {
      float ig = sigmoidf_(gs2[tid]);
      float fg = sigmoidf_(gs2[LSTM2_H + tid]);
      float gg = tanhf_(gs2[2 * LSTM2_H + tid]);
      float og = sigmoidf_(gs2[3 * LSTM2_H + tid]);
      float c = fg * cs2[tid] + ig * gg;
      cs2[tid] = c;
      float h = og * tanhf_(c);
      hs2h[tid] = (_Float16)h;
      hs2f[tid] = h;
    }
    __syncthreads();
  }

  if (tid < 4) {
    float acc = fcb[tid];
    #pragma unroll
    for (int k = 0; k < LSTM2_H; ++k) acc += fcW[tid * LSTM2_H + k] * hs2f[k];
    out[b * 4 + tid] = acc;
  }
}

// ============================================================
extern "C" void kernel_launch(void* const* d_in, const int* in_sizes, int n_in,
                              void* d_out, int out_size, void* d_ws, size_t ws_size,
                              hipStream_t stream) {
  const float* x       = (const float*)d_in[0];
  const int*   eidx    = (const int*)d_in[1];
  const float* eattr   = (const float*)d_in[2];
  const float* g1_Wl   = (const float*)d_in[3];
  const float* g1_Wr   = (const float*)d_in[4];
  const float* g1_We   = (const float*)d_in[5];
  const float* g1_att  = (const float*)d_in[6];
  const float* g1_b    = (const float*)d_in[7];
  const float* g2_Wl   = (const float*)d_in[8];
  const float* g2_Wr   = (const float*)d_in[9];
  const float* g2_We   = (const float*)d_in[10];
  const float* g2_att  = (const float*)d_in[11];
  const float* g2_b    = (const float*)d_in[12];
  const float* l1_Wih  = (const float*)d_in[13];
  const float* l1_Whh  = (const float*)d_in[14];
  const float* l1_bih  = (const float*)d_in[15];
  const float* l1_bhh  = (const float*)d_in[16];
  const float* l2_Wih  = (const float*)d_in[17];
  const float* l2_Whh  = (const float*)d_in[18];
  const float* l2_bih  = (const float*)d_in[19];
  const float* l2_bhh  = (const float*)d_in[20];
  const float* fc_W    = (const float*)d_in[21];
  const float* fc_b    = (const float*)d_in[22];
  float* out = (float*)d_out;

  const int* src = eidx;
  const int* dst = eidx + E_EDGES;

  // ---- runtime-adaptive chunking (all chunk_n divisible by 128) ----
  const int cand[4] = {1, 2, 3, 6};
  int nchunks = 0;
  half_t *h1 = nullptr, *xlr2c = nullptr, *h2 = nullptr, *B2 = nullptr, *W1f = nullptr;
  float *X1p = nullptr;
  int chunk_g = 0, chunk_n = 0;
  for (int ci = 0; ci < 4; ++ci) {
    int C = cand[ci];
    int CG = G_GRAPHS / C, CN = CG * N_NODES;
    char* p = (char*)d_ws;
    auto alloc = [&](size_t bytes) { char* r = p; p += (bytes + 255) & ~(size_t)255; return r; };
    half_t* t_h1    = (half_t*)alloc((size_t)CN * HC * 2);
    half_t* t_xlr2c = (half_t*)alloc((size_t)CN * 1024 * 2);
    half_t* t_h2    = (half_t*)alloc((size_t)G_GRAPHS * 2112 * 2);
    half_t* t_B2    = (half_t*)alloc((size_t)1024 * 512 * 2);
    half_t* t_W1f   = (half_t*)alloc((size_t)512 * 2112 * 2);
    float*  t_X1p   = (float*)alloc((size_t)4 * G_GRAPHS * 512 * 4);
    if ((size_t)(p - (char*)d_ws) <= ws_size) {
      nchunks = C; chunk_g = CG; chunk_n = CN;
      h1 = t_h1; xlr2c = t_xlr2c; h2 = t_h2; B2 = t_B2; W1f = t_W1f;
      X1p = t_X1p;
      break;
    }
  }
  if (nchunks == 0) return;   // guard: zero output instead of memory fault

  for (int c = 0; c < nchunks; ++c) {
    int g0 = c * chunk_g;
    int extra = (c == 0) ? CONV_BLOCKS : 0;
    gat1_kernel<<<chunk_g + extra, 512, 0, stream>>>(
        x, src, dst, eattr, g1_Wl, g1_Wr, g1_We, g1_att, g1_b, h1, g0, chunk_g,
        g2_Wl, g2_Wr, B2, l1_Wih, W1f);
    int gblocks = (chunk_n / 128) * 8;    // % 8 == 0 for all chunk candidates
    gemm_m97<<<gblocks, 256, 0, stream>>>(h1, B2, xlr2c, chunk_n);
    gat2_kernel<<<chunk_g, 512, 0, stream>>>(xlr2c, src, dst, eattr, g2_We,
                                             g2_att, g2_b, h2, g0);
  }

  // X1 partials = h2 @ l1_Wih^T (+biases in part 0), split-K=4, one dispatch
  {
    dim3 grid(192, 4);
    gemm_f16_splitk<<<grid, 256, 0, stream>>>(h2, W1f, X1p, l1_bih, l1_bhh,
                                              G_GRAPHS, 512);
  }

  // fused LSTM1 + x2 + LSTM2 + FC
  {
    size_t PS = (size_t)G_GRAPHS * 512;
    lstm_all<<<BATCH, 512, 0, stream>>>(X1p, X1p + PS, X1p + 2 * PS, X1p + 3 * PS,
                                        l1_Whh, l2_Wih, l2_bih, l2_bhh, l2_Whh,
                                        fc_W, fc_b, out);
  }
}